// Round 9
// baseline (58.774 us; speedup 1.0000x reference)
//
#include <hip/hip_runtime.h>

// Problem constants (from reference)
constexpr int B = 8;
constexpr int N = 8192;
constexpr int K = 2048;
constexpr int C = 64;
constexpr int NS = 32;            // N_SAMPLE
#define RAD2 0.0625f              // RADIUS^2, exact in fp32

typedef float  fx4 __attribute__((ext_vector_type(4)));
typedef int    ix4 __attribute__((ext_vector_type(4)));
typedef unsigned long long ull;

// ---------------------------------------------------------------------------
// Kernel P: pack points as (x, y, z, |p|^2) so the scan does ONE dwordx4 load
// and ~10 VALU per point instead of 3 loads + 13 VALU. pp computed in the
// exact reference order (x*x + y*y) + z*z, fp32, contract off.
// ---------------------------------------------------------------------------
__global__ __launch_bounds__(256) void pack_points_kernel(
    const float* __restrict__ points,  // (B, N, 3)
    fx4* __restrict__ pts4)            // (B, N) of (x,y,z,pp)
{
#pragma clang fp contract(off)
    const int i = blockIdx.x * blockDim.x + threadIdx.x;  // < B*N
    const float p0 = points[(size_t)i * 3 + 0];
    const float p1 = points[(size_t)i * 3 + 1];
    const float p2 = points[(size_t)i * 3 + 2];
    fx4 v;
    v.x = p0; v.y = p1; v.z = p2;
    v.w = (p0 * p0 + p1 * p1) + p2 * p2;
    pts4[i] = v;
}

// ---------------------------------------------------------------------------
// Kernel A v6: ball query, one wave per centroid.
// Phase 1: first 1024 points, ALL 16 fx4 loads issued up-front (no break in
// between -> full memory-level parallelism), ballots recorded to LDS.
// Straggler loop: 256 points/iter, 4 loads up-front, single break per iter.
// Epilogue: lanes 0..31 locate their j-th hit in the recorded masks and do
// coalesced idx + 3-plane gp stores.
// d2 = (cc + pp) - 2*cp, fp32, contract off, numpy add order — bit-exact.
// ---------------------------------------------------------------------------
__global__ __launch_bounds__(128) void ballquery_gp_kernel(
    const fx4* __restrict__ pts4,         // (B, N): x,y,z,pp
    const float* __restrict__ centroids,  // (B, K, 3)
    float* __restrict__ gp_out,           // (B, 3, K, NS)
    int* __restrict__ idx_ws)             // (B, K, NS)
{
#pragma clang fp contract(off)
    __shared__ ull masks_s[2][N / 64];
    const int wave = (blockIdx.x * blockDim.x + threadIdx.x) >> 6;
    const int lane = threadIdx.x & 63;
    if (wave >= B * K) return;
    const int b = wave >> 11;            // K = 2048
    const int k = wave & (K - 1);
    ull* mk = masks_s[threadIdx.x >> 6];

    const float* cptr = centroids + (size_t)(b * K + k) * 3;
    const float c0 = cptr[0], c1 = cptr[1], c2 = cptr[2];
    const float cc = (c0 * c0 + c1 * c1) + c2 * c2;

    const fx4* p4 = pts4 + (size_t)b * N;

    int count = 0;

    // ---- Phase 1: 1024 points, loads fully issued before any use ----
    fx4 buf[16];
#pragma unroll
    for (int gg = 0; gg < 16; ++gg)
        buf[gg] = p4[gg * 64 + lane];
#pragma unroll
    for (int gg = 0; gg < 16; ++gg) {
        const float cp = (c0 * buf[gg].x + c1 * buf[gg].y) + c2 * buf[gg].z;
        const float d2 = (cc + buf[gg].w) - 2.0f * cp;
        const ull m = __ballot(d2 < RAD2);
        if (lane == 0) mk[gg] = m;
        count += __popcll(m);
    }

    // ---- Straggler loop: 256 points/iter, one break per iter ----
    if (count < NS) {
        int g = 16;
        for (int base = 1024; base < N; base += 256) {
            const fx4 s0 = p4[base + lane];
            const fx4 s1 = p4[base + 64 + lane];
            const fx4 s2 = p4[base + 128 + lane];
            const fx4 s3 = p4[base + 192 + lane];

            const float cpa = (c0 * s0.x + c1 * s0.y) + c2 * s0.z;
            const float cpb = (c0 * s1.x + c1 * s1.y) + c2 * s1.z;
            const float cpc = (c0 * s2.x + c1 * s2.y) + c2 * s2.z;
            const float cpd = (c0 * s3.x + c1 * s3.y) + c2 * s3.z;
            const ull m0 = __ballot(((cc + s0.w) - 2.0f * cpa) < RAD2);
            const ull m1 = __ballot(((cc + s1.w) - 2.0f * cpb) < RAD2);
            const ull m2 = __ballot(((cc + s2.w) - 2.0f * cpc) < RAD2);
            const ull m3 = __ballot(((cc + s3.w) - 2.0f * cpd) < RAD2);
            if (lane == 0) {
                mk[g] = m0; mk[g + 1] = m1; mk[g + 2] = m2; mk[g + 3] = m3;
            }
            count += __popcll(m0) + __popcll(m1) + __popcll(m2) + __popcll(m3);
            g += 4;
            if (count >= NS) break;  // wave-uniform
        }
    }

    // ---- Epilogue: lanes 0..31 each produce output slot `lane` ----
    if (lane < NS) {
        const int cnt = count < NS ? count : NS;
        int i = 0;
        if (count > 0) {
            const int target = (lane < cnt) ? lane : 0;  // pad slots use hit #0
            int running = 0;
            int gg = 0;
            ull m;
            for (;; ++gg) {  // terminates: cumulative popc reaches count > target
                m = mk[gg];
                const int c = __popcll(m);
                if (running + c > target) break;
                running += c;
            }
            int r = target - running;
            for (int t = 0; t < r; ++t) m &= m - 1;  // clear r lowest set bits
            i = gg * 64 + __builtin_ctzll(m);
        }
        const fx4 p = p4[i];
        idx_ws[(size_t)wave * NS + lane] = i;
        float* gpb = gp_out + ((size_t)b * 3 * K + k) * NS;
        gpb[0 * K * NS + lane] = (p.x - c0) * 4.0f;
        gpb[1 * K * NS + lane] = (p.y - c1) * 4.0f;
        gpb[2 * K * NS + lane] = (p.z - c2) * 4.0f;
    }
}

// ---------------------------------------------------------------------------
// Kernel B (unchanged): one block per (b,c); 32 KB feature row in LDS;
// idx int4 prefetch; nontemporal streaming stores.
// ---------------------------------------------------------------------------
__global__ __launch_bounds__(1024) void gather_feats_lds(
    const float* __restrict__ features,  // (B, C, N)
    const int* __restrict__ idx_ws,      // (B, K, NS)
    float* __restrict__ nf_out)          // (B, C, K, NS)
{
    __shared__ float row[N];  // 32 KB
    const int bc = blockIdx.x;
    const int t = threadIdx.x;

    {
        const fx4* frow4 = reinterpret_cast<const fx4*>(features + (size_t)bc * N);
        fx4* row4 = reinterpret_cast<fx4*>(row);
#pragma unroll
        for (int j = 0; j < 2; ++j)
            row4[t + j * 1024] = __builtin_nontemporal_load(&frow4[t + j * 1024]);
    }
    __syncthreads();

    const int b = bc >> 6;               // C = 64
    const int* idxb = idx_ws + (size_t)b * K * NS;
    float* outb = nf_out + (size_t)bc * K * NS;

    ix4 iv = *reinterpret_cast<const ix4*>(idxb + (size_t)t * 4);
#pragma unroll
    for (int j = 0; j < 16; ++j) {
        const int g = j * 1024 + t;
        ix4 ivn;
        if (j < 15)
            ivn = *reinterpret_cast<const ix4*>(idxb + (size_t)(g + 1024) * 4);
        fx4 v;
        v.x = row[iv.x];
        v.y = row[iv.y];
        v.z = row[iv.z];
        v.w = row[iv.w];
        __builtin_nontemporal_store(v, reinterpret_cast<fx4*>(outb + (size_t)g * 4));
        if (j < 15) iv = ivn;
    }
}

extern "C" void kernel_launch(void* const* d_in, const int* in_sizes, int n_in,
                              void* d_out, int out_size, void* d_ws, size_t ws_size,
                              hipStream_t stream) {
    const float* points    = (const float*)d_in[0];
    const float* centroids = (const float*)d_in[1];
    const float* features  = (const float*)d_in[2];
    float* out = (float*)d_out;

    float* gp_out = out;                              // B*3*K*NS floats
    float* nf_out = out + (size_t)B * 3 * K * NS;     // B*C*K*NS floats

    // ws layout: [0,2MB) idx | [4MB,5MB) pts4
    int* idx_ws = (int*)d_ws;
    fx4* pts4   = (fx4*)((char*)d_ws + ((size_t)4 << 20));

    // Kernel P: pack (x,y,z,pp)
    hipLaunchKernelGGL(pack_points_kernel, dim3(B * N / 256), dim3(256), 0, stream,
                       points, pts4);

    // Kernel A: one wave per centroid
    const int waves = B * K;                          // 16384
    hipLaunchKernelGGL(ballquery_gp_kernel, dim3(waves / 2), dim3(128), 0, stream,
                       pts4, centroids, gp_out, idx_ws);

    // Kernel B
    hipLaunchKernelGGL(gather_feats_lds, dim3(B * C), dim3(1024), 0, stream,
                       features, idx_ws, nf_out);
}